// Round 6
// baseline (5034.732 us; speedup 1.0000x reference)
//
#include <hip/hip_runtime.h>
#include <hip/hip_fp16.h>
#include <cstddef>
#include <cstdint>

#define B_  256
#define T_  512
#define D_  128
#define H_  256
#define G3_ 768
#define C_  10

typedef _Float16 f16x8 __attribute__((ext_vector_type(8)));
typedef float    f32x4 __attribute__((ext_vector_type(4)));

__device__ __forceinline__ float sigmoid_f(float x) {
    return 1.0f / (1.0f + __expf(-x));
}
__device__ __forceinline__ float tanh_f(float x) {
    return 1.0f - 2.0f / (__expf(2.0f * x) + 1.0f);
}

__device__ __forceinline__ unsigned int packh2(float a, float b) {
    unsigned short lo = __half_as_ushort(__float2half(a));   // k even -> lo16
    unsigned short hi = __half_as_ushort(__float2half(b));   // k odd  -> hi16
    return (unsigned int)lo | ((unsigned int)hi << 16);
}

// ---------------------------------------------------------------------------
// Pack Whh[3H][H] fp32 -> f16 MFMA B-fragment stream for the scan.
// Fragment (w8, nt, kt): column-set w8 owns gate-cols g*256 + w8*32 + (nt&1)*16
// (g = nt>>1), K-tile kt. Lane l: n = c0 + (l&15), k = kt*32 + (l>>4)*8 + i.
// (unchanged, harness-verified layout)
// ---------------------------------------------------------------------------
__global__ void k_pack_whh(const float* __restrict__ Whh, uint4* __restrict__ Wl) {
    const int wnt = blockIdx.x;          // w8*6 + nt
    const int w  = wnt / 6;
    const int nt = wnt % 6;
    const int t  = threadIdx.x;
    const int kt = t >> 6;
    const int l  = t & 63;
    const int g  = nt >> 1;
    const int n  = g * 256 + w * 32 + (nt & 1) * 16 + (l & 15);
    const int k0 = kt * 32 + (l >> 4) * 8;
    const float* row = Whh + (size_t)n * H_ + k0;
    uint4 u;
    u.x = packh2(row[0], row[1]);
    u.y = packh2(row[2], row[3]);
    u.z = packh2(row[4], row[5]);
    u.w = packh2(row[6], row[7]);
    Wl[(size_t)wnt * 512 + t] = u;
}

// ---------------------------------------------------------------------------
// Pack Wih[768][K] fp32 -> f16 B-fragments for the gi GEMM. (unchanged)
// ---------------------------------------------------------------------------
__global__ void k_pack_wih(const float* __restrict__ W, uint4* __restrict__ Wp,
                           int K) {
    const int KT = K >> 5;
    const int f  = blockIdx.x * 4 + (threadIdx.x >> 6);
    const int l  = threadIdx.x & 63;
    const int ntile = f / KT;
    const int kt    = f - ntile * KT;
    const int n  = ntile * 16 + (l & 15);
    const int k0 = kt * 32 + (l >> 4) * 8;
    const float* row = W + (size_t)n * K + k0;
    uint4 u;
    u.x = packh2(row[0], row[1]);
    u.y = packh2(row[2], row[3]);
    u.z = packh2(row[4], row[5]);
    u.w = packh2(row[6], row[7]);
    Wp[(size_t)f * 64 + l] = u;
}

// ---------------------------------------------------------------------------
// gi GEMM on the matrix pipe (unchanged from R4; ~60-70 us/dispatch).
// ---------------------------------------------------------------------------
__global__ __launch_bounds__(256) void k_gemm_f16(
    const float* __restrict__ A, long Abstride, int tcShift,
    const uint4* __restrict__ Wp,
    const float* __restrict__ bias, float* __restrict__ C,
    int K)
{
    const int tid = threadIdx.x;
    const int w  = tid >> 6;
    const int l  = tid & 63;
    const int c  = l & 15;
    const int g4 = l >> 4;
    const int m0 = blockIdx.y * 128;
    const int n0 = blockIdx.x * 64;
    const int KT = K >> 5;
    const int mask = (1 << tcShift) - 1;

    const float* Arow0;
    const float* Arow1;
    {
        int mg0 = m0 + w * 32 + c;
        int mg1 = mg0 + 16;
        Arow0 = A + (size_t)(mg0 >> tcShift) * Abstride + (size_t)(mg0 & mask) * K + g4 * 8;
        Arow1 = A + (size_t)(mg1 >> tcShift) * Abstride + (size_t)(mg1 & mask) * K + g4 * 8;
    }
    const uint4* Wb = Wp + (size_t)((n0 >> 4) * KT) * 64 + l;

    f32x4 acc[2][4] = {};

    for (int kt = 0; kt < KT; kt++) {
        f16x8 a0, a1;
        {
            float4 lo = *(const float4*)(Arow0 + kt * 32);
            float4 hi = *(const float4*)(Arow0 + kt * 32 + 4);
            a0[0] = (_Float16)lo.x; a0[1] = (_Float16)lo.y;
            a0[2] = (_Float16)lo.z; a0[3] = (_Float16)lo.w;
            a0[4] = (_Float16)hi.x; a0[5] = (_Float16)hi.y;
            a0[6] = (_Float16)hi.z; a0[7] = (_Float16)hi.w;
        }
        {
            float4 lo = *(const float4*)(Arow1 + kt * 32);
            float4 hi = *(const float4*)(Arow1 + kt * 32 + 4);
            a1[0] = (_Float16)lo.x; a1[1] = (_Float16)lo.y;
            a1[2] = (_Float16)lo.z; a1[3] = (_Float16)lo.w;
            a1[4] = (_Float16)hi.x; a1[5] = (_Float16)hi.y;
            a1[6] = (_Float16)hi.z; a1[7] = (_Float16)hi.w;
        }
#pragma unroll
        for (int ct = 0; ct < 4; ct++) {
            uint4 wf = Wb[(size_t)(ct * KT + kt) * 64];
            acc[0][ct] = __builtin_amdgcn_mfma_f32_16x16x32_f16(
                a0, __builtin_bit_cast(f16x8, wf), acc[0][ct], 0, 0, 0);
            acc[1][ct] = __builtin_amdgcn_mfma_f32_16x16x32_f16(
                a1, __builtin_bit_cast(f16x8, wf), acc[1][ct], 0, 0, 0);
        }
    }

#pragma unroll
    for (int ct = 0; ct < 4; ct++) {
        const int n = n0 + ct * 16 + c;
        const float bv = bias[n];
#pragma unroll
        for (int rt = 0; rt < 2; rt++) {
#pragma unroll
            for (int rg = 0; rg < 4; rg++) {
                const int m = m0 + w * 32 + rt * 16 + g4 * 4 + rg;
                C[(size_t)m * G3_ + n] = acc[rt][ct][rg] + bv;
            }
        }
    }
}

// ---------------------------------------------------------------------------
// PARTNER-SPLIT MFMA scan. 64 blocks x 256 thr (4 waves), 1 block/CU.
// Block = (col-half s = blk>>5, grp = blk&31; layer = grp>>4, 16-row group
// rg = grp&15). Partner = blk ^ 32 (same XCD residue). Block owns h-cols
// [s*128, s*128+128) -> 384 gate cols -> 192 KB f16 weights, FULLY RESIDENT:
// nt 0,1 = 16 frags/lane (64 VGPR), nt 2..5 = 128 KB LDS. This kills the
// 256 KB/step/CU L2 weight stream (R1-R3: the measured ~4,100 cy/step wall).
// NOTE R5: the wreg launder MUST be typed f16x8 -- "+v" on a uint4 array
// element fails to compile ("tied indirect register inputs"); the f16x8
// form compiled in R2. With 4 waves/CU the per-wave VGPR budget is ~512,
// so no R2-style AGPR-shuttle risk.
// Per step the pair exchanges h-halves (4 KB) via agent-scope atomics in L2:
//   publish: packed-u32 stores -> threadfence -> barrier -> flag (release)
//   consume: spin flag (bounded) -> barrier -> 4 u32 loads -> lds_h patch
// Dep-2 hx parity is safe: this step's clobber of parity p requires partner
// wflag >= S, established by THIS step's (or stream-order's) spin.
// Last step of a chunk publishes nothing (next chunk re-inits from h_state;
// launches are stream-ordered).
// ---------------------------------------------------------------------------
__device__ __forceinline__ void gru_scan_core(
    const float* __restrict__ gi,      // + b0*Tc*G3   [16 rows][Tc][3H]
    const uint4* __restrict__ Wpk,     // [8*6*8][64] packed B-fragments
    const float* __restrict__ bhh,
    float* __restrict__ h_state,       // + b0*H
    float* __restrict__ out_seq,       // + b0*Tc*H or nullptr
    unsigned int* __restrict__ hx,     // [2][64][16][64] u32 pair-packed
    int* __restrict__ flags,           // [64*16] (64B-strided)
    int blk, int par, int s, int Tc, int initZero, int base,
    uint4 (&lds_w)[8192], _Float16 (&lds_h)[2][16][264])
{
    const int tid = threadIdx.x;
    const int w  = tid >> 6;       // wave 0..3
    const int l  = tid & 63;
    const int c  = l & 15;
    const int g4 = l >> 4;         // 0..3
    const int w8 = s * 4 + w;      // global column-set 0..7

    // ---- stage LDS-resident weight frags: nt 2..5 of each wave ------------
#pragma unroll
    for (int i = 0; i < 32; i++) {
        int idx = i * 256 + tid;                   // [0, 8192)
        int set = idx >> 11;                       // wave col-set 0..3
        int fi  = (idx >> 6) & 31;                 // (nt-2)*8 + kt
        int ln  = idx & 63;
        int nt  = 2 + (fi >> 3);
        int kt  = fi & 7;
        lds_w[idx] = Wpk[(size_t)(((s * 4 + set) * 6 + nt) * 8 + kt) * 64 + ln];
    }

    // ---- register-resident frags: nt 0,1 x kt 0..7 -> 64 VGPRs ------------
    f16x8 wreg[16];
#pragma unroll
    for (int nt = 0; nt < 2; nt++)
#pragma unroll
        for (int kt = 0; kt < 8; kt++)
            wreg[nt * 8 + kt] = *reinterpret_cast<const f16x8*>(
                Wpk + (size_t)((w8 * 6 + nt) * 8 + kt) * 64 + l);

    // ---- lane ownership: m = g4*4+r, own cols jA, jA+16 -------------------
    const int jA  = s * 128 + w * 32 + c;          // own column
    const int jAo = (s ^ 1) * 128 + w * 32 + c;    // partner-mirror column
    const float br0 = bhh[jA],       br1 = bhh[jA + 16];
    const float bz0 = bhh[256 + jA], bz1 = bhh[256 + jA + 16];
    const float bn0 = bhh[512 + jA], bn1 = bhh[512 + jA + 16];

    float hreg[4][2];
#pragma unroll
    for (int r = 0; r < 4; r++) {
        const int m = g4 * 4 + r;
        if (initZero) {
            hreg[r][0] = 0.0f;
            hreg[r][1] = 0.0f;
        } else {
            hreg[r][0] = h_state[(size_t)m * H_ + jA];
            hreg[r][1] = h_state[(size_t)m * H_ + jA + 16];
        }
    }
    // full-width h_{-1} init (both halves) from h_state / zero
    {
        const int row = tid >> 4;
        const int cc  = (tid & 15) * 16;
        _Float16 tmp[16];
        if (initZero) {
#pragma unroll
            for (int i = 0; i < 16; i++) tmp[i] = (_Float16)0.0f;
        } else {
            const float* hp = h_state + (size_t)row * H_ + cc;
#pragma unroll
            for (int i = 0; i < 16; i++) tmp[i] = (_Float16)hp[i];
        }
        *(uint4*)&lds_h[0][row][cc]     = *(const uint4*)&tmp[0];
        *(uint4*)&lds_h[0][row][cc + 8] = *(const uint4*)&tmp[8];
    }
    __syncthreads();

    int cur = 0;
    for (int tt = 0; tt < Tc; ++tt) {
        const int S = base + tt;
        const bool lastStep = (tt == Tc - 1);

        // anti-remat launder (f16x8 form -- uint4 form does not compile)
#pragma unroll
        for (int i = 0; i < 16; i++)
            asm volatile("" : "+v"(wreg[i]));
        unsigned wb = (unsigned)(w * 2048 + l);
        asm volatile("" : "+v"(wb));

        // gi prefetch: issued now, consumed after the MFMA block.
        float gic[4][6];
#pragma unroll
        for (int r = 0; r < 4; r++) {
            const float* gp = gi + ((size_t)(g4 * 4 + r) * Tc + tt) * G3_ + jA;
#pragma unroll
            for (int gg = 0; gg < 3; gg++) {
                gic[r][gg * 2 + 0] = gp[gg * 256];
                gic[r][gg * 2 + 1] = gp[gg * 256 + 16];
            }
        }

        // ---- partner h_{tt-1} arrival -------------------------------------
        if (tt > 0) {
            if (tid == 0) {
                int guard = 0;
                while (__hip_atomic_load(&flags[par * 16], __ATOMIC_ACQUIRE,
                                         __HIP_MEMORY_SCOPE_AGENT) < S &&
                       guard < (1 << 20)) guard++;
            }
            __syncthreads();
            const unsigned pb = ((unsigned)((S - 1) & 1) * 64 + (unsigned)par) * 16;
            unsigned pv[4];
#pragma unroll
            for (int r = 0; r < 4; r++)
                pv[r] = __hip_atomic_load(
                    &hx[(pb + g4 * 4 + r) * 64 + w * 16 + c],
                    __ATOMIC_RELAXED, __HIP_MEMORY_SCOPE_AGENT);
#pragma unroll
            for (int r = 0; r < 4; r++) {
                const int m = g4 * 4 + r;
                lds_h[cur][m][jAo] =
                    __builtin_bit_cast(_Float16, (unsigned short)(pv[r] & 0xffffu));
                lds_h[cur][m][jAo + 16] =
                    __builtin_bit_cast(_Float16, (unsigned short)(pv[r] >> 16));
            }
        }
        __syncthreads();

        // ---- 48 MFMA: 16 from regs (nt 0,1) + 32 from LDS (nt 2..5) -------
        f32x4 acc[6] = {};
#pragma unroll
        for (int kt = 0; kt < 8; kt++) {
            f16x8 a = *(const f16x8*)&lds_h[cur][c][kt * 32 + g4 * 8];
            acc[0] = __builtin_amdgcn_mfma_f32_16x16x32_f16(
                a, wreg[kt], acc[0], 0, 0, 0);
            acc[1] = __builtin_amdgcn_mfma_f32_16x16x32_f16(
                a, wreg[8 + kt], acc[1], 0, 0, 0);
#pragma unroll
            for (int nt = 2; nt < 6; nt++) {
                uint4 u = lds_w[wb + ((nt - 2) * 8 + kt) * 64];
                acc[nt] = __builtin_amdgcn_mfma_f32_16x16x32_f16(
                    a, __builtin_bit_cast(f16x8, u), acc[nt], 0, 0, 0);
            }
        }

        // ---- gates + own-half h update + publish --------------------------
#pragma unroll
        for (int r = 0; r < 4; r++) {
            const int m = g4 * 4 + r;
            _Float16 q[2];
#pragma unroll
            for (int jj = 0; jj < 2; jj++) {
                float rg = sigmoid_f(gic[r][jj]     + acc[jj][r]     + (jj ? br1 : br0));
                float zg = sigmoid_f(gic[r][2 + jj] + acc[2 + jj][r] + (jj ? bz1 : bz0));
                float ng = tanh_f(gic[r][4 + jj] +
                                  rg * (acc[4 + jj][r] + (jj ? bn1 : bn0)));
                float hn = (1.0f - zg) * ng + zg * hreg[r][jj];
                hreg[r][jj] = hn;
                q[jj] = (_Float16)hn;
                lds_h[cur ^ 1][m][jA + jj * 16] = q[jj];
                if (out_seq)
                    out_seq[((size_t)m * Tc + tt) * H_ + jA + jj * 16] = hn;
            }
            if (!lastStep) {
                unsigned pk =
                    (unsigned)__builtin_bit_cast(unsigned short, q[0]) |
                    ((unsigned)__builtin_bit_cast(unsigned short, q[1]) << 16);
                __hip_atomic_store(
                    &hx[(((unsigned)(S & 1) * 64 + (unsigned)blk) * 16 + m) * 64 +
                        w * 16 + c],
                    pk, __ATOMIC_RELAXED, __HIP_MEMORY_SCOPE_AGENT);
            }
        }
        if (lastStep) {
#pragma unroll
            for (int r = 0; r < 4; r++) {
                const int m = g4 * 4 + r;
                h_state[(size_t)m * H_ + jA]      = hreg[r][0];
                h_state[(size_t)m * H_ + jA + 16] = hreg[r][1];
            }
        } else {
            __threadfence();
            __syncthreads();
            if (tid == 0)
                __hip_atomic_store(&flags[blk * 16], S + 1, __ATOMIC_RELEASE,
                                   __HIP_MEMORY_SCOPE_AGENT);
        }
        cur ^= 1;
    }
}

__global__ __launch_bounds__(256, 1) void k_gru_scan_fused(
    const float* __restrict__ gi0, const uint4* __restrict__ wl0,
    const float* __restrict__ bhh0, float* __restrict__ hst0,
    float* __restrict__ h1c,
    const float* __restrict__ gi1, const uint4* __restrict__ wl1,
    const float* __restrict__ bhh1, float* __restrict__ hst1,
    unsigned int* __restrict__ hx, int* __restrict__ flags,
    int Tc, int do0, int do1, int init0, int init1, int base0, int base1)
{
    __shared__ __align__(16) uint4    lds_w[8192];        // 128 KB
    __shared__ __align__(16) _Float16 lds_h[2][16][264];  // 16.5 KB

    const int blk = blockIdx.x;
    const int s   = blk >> 5;
    const int grp = blk & 31;
    const int par = blk ^ 32;       // same-layer, same-rows, other col-half
    const int layer = grp >> 4;
    const int b0 = (grp & 15) * 16;

    if (layer == 0) {
        if (!do0) return;
        gru_scan_core(gi0 + (size_t)b0 * Tc * G3_, wl0, bhh0,
                      hst0 + (size_t)b0 * H_, h1c + (size_t)b0 * Tc * H_,
                      hx, flags, blk, par, s, Tc, init0, base0, lds_w, lds_h);
    } else {
        if (!do1) return;
        gru_scan_core(gi1 + (size_t)b0 * Tc * G3_, wl1, bhh1,
                      hst1 + (size_t)b0 * H_, nullptr,
                      hx, flags, blk, par, s, Tc, init1, base1, lds_w, lds_h);
    }
}

// ---------------------------------------------------------------------------
__global__ void k_fc(const float* __restrict__ h, const float* __restrict__ Wfc,
                     const float* __restrict__ bfc, float* __restrict__ out)
{
    int idx = blockIdx.x * blockDim.x + threadIdx.x;
    if (idx >= B_ * C_) return;
    int b = idx / C_, c = idx % C_;
    const float* hp = h + (size_t)b * H_;
    const float* wp = Wfc + (size_t)c * H_;
    float s = bfc[c];
#pragma unroll 4
    for (int k = 0; k < H_; k++) s = fmaf(hp[k], wp[k], s);
    out[idx] = s;
}

// ---------------------------------------------------------------------------
extern "C" void kernel_launch(void* const* d_in, const int* in_sizes, int n_in,
                              void* d_out, int out_size, void* d_ws, size_t ws_size,
                              hipStream_t stream)
{
    const float* x    = (const float*)d_in[0];
    const float* Wih0 = (const float*)d_in[1];
    const float* Whh0 = (const float*)d_in[2];
    const float* bih0 = (const float*)d_in[3];
    const float* bhh0 = (const float*)d_in[4];
    const float* Wih1 = (const float*)d_in[5];
    const float* Whh1 = (const float*)d_in[6];
    const float* bih1 = (const float*)d_in[7];
    const float* bhh1 = (const float*)d_in[8];
    const float* Wfc  = (const float*)d_in[9];
    const float* bfc  = (const float*)d_in[10];
    float* out = (float*)d_out;

    const size_t wlBytes  = (size_t)48 * 512 * sizeof(uint4);    // 393,216 B
    const size_t wp0Bytes = (size_t)48 * 4 * 64 * sizeof(uint4); // 196,608 B
    const size_t wp1Bytes = (size_t)48 * 8 * 64 * sizeof(uint4); // 393,216 B
    const size_t hxBytes  = (size_t)2 * 64 * 16 * 64 * 4;        // 524,288 B
    const size_t flBytes  = (size_t)64 * 16 * 4;                 // 4,096 B

    // ---- largest power-of-two T-chunk that fits ws_size -------------------
    const size_t fixedB = 2 * wlBytes + wp0Bytes + wp1Bytes + hxBytes + flBytes
                        + 2 * (size_t)B_ * H_ * 4 + 16384;
    int Tc = 128, tcShift = 7;
    while (Tc > 1) {
        size_t need = fixedB
                    + 2 * (size_t)B_ * Tc * G3_ * 4    // gi0, gi1 chunks
                    + (size_t)B_ * Tc * H_ * 4;        // h1 chunk
        if (need <= ws_size) break;
        Tc >>= 1; tcShift--;
    }
    const int nChunks = T_ / Tc;

    char* ws = (char*)d_ws;
    size_t off = 0;
    auto alloc = [&](size_t bytes) { char* p = ws + off; off += (bytes + 255) & ~(size_t)255; return p; };
    float* gi0  = (float*)alloc((size_t)B_ * Tc * G3_ * 4);
    float* gi1  = (float*)alloc((size_t)B_ * Tc * G3_ * 4);
    float* h1c  = (float*)alloc((size_t)B_ * Tc * H_ * 4);
    uint4* wl0  = (uint4*)alloc(wlBytes);
    uint4* wl1  = (uint4*)alloc(wlBytes);
    uint4* wp0  = (uint4*)alloc(wp0Bytes);
    uint4* wp1  = (uint4*)alloc(wp1Bytes);
    float* hst0 = (float*)alloc((size_t)B_ * H_ * 4);
    float* hst1 = (float*)alloc((size_t)B_ * H_ * 4);
    unsigned int* hx = (unsigned int*)alloc(hxBytes);
    int* flags  = (int*)alloc(flBytes);

    hipMemsetAsync(flags, 0, flBytes, stream);

    k_pack_whh<<<48, 512, 0, stream>>>(Whh0, wl0);
    k_pack_whh<<<48, 512, 0, stream>>>(Whh1, wl1);
    k_pack_wih<<<48, 256, 0, stream>>>(Wih0, wp0, D_);   // KT=4 -> 192 frags
    k_pack_wih<<<96, 256, 0, stream>>>(Wih1, wp1, H_);   // KT=8 -> 384 frags

    const dim3 ggrid(G3_ / 64, (B_ * Tc) / 128);

    // software pipeline: fused launch c runs scan0(c) and scan1(c-1)
    k_gemm_f16<<<ggrid, 256, 0, stream>>>(
        x, (long)T_ * D_, tcShift, wp0, bih0, gi0, D_);
    k_gru_scan_fused<<<64, 256, 0, stream>>>(
        gi0, wl0, bhh0, hst0, h1c, gi1, wl1, bhh1, hst1, hx, flags,
        Tc, 1, 0, 1, 0, 0, 0);

    for (int c = 1; c < nChunks; ++c) {
        k_gemm_f16<<<ggrid, 256, 0, stream>>>(
            h1c, (long)Tc * H_, tcShift, wp1, bih1, gi1, H_);        // chunk c-1
        k_gemm_f16<<<ggrid, 256, 0, stream>>>(
            x + (size_t)c * Tc * D_, (long)T_ * D_, tcShift, wp0, bih0, gi0, D_);
        k_gru_scan_fused<<<64, 256, 0, stream>>>(
            gi0, wl0, bhh0, hst0, h1c, gi1, wl1, bhh1, hst1, hx, flags,
            Tc, 1, 1, 0, c == 1, c * Tc, (c - 1) * Tc);
    }

    k_gemm_f16<<<ggrid, 256, 0, stream>>>(
        h1c, (long)Tc * H_, tcShift, wp1, bih1, gi1, H_);            // last chunk
    k_gru_scan_fused<<<64, 256, 0, stream>>>(
        gi0, wl0, bhh0, hst0, h1c, gi1, wl1, bhh1, hst1, hx, flags,
        Tc, 0, 1, 0, nChunks == 1, 0, (nChunks - 1) * Tc);

    k_fc<<<10, 256, 0, stream>>>(hst1, Wfc, bfc, out);
}

// Round 7
// 3583.866 us; speedup vs baseline: 1.4048x; 1.4048x over previous
//
#include <hip/hip_runtime.h>
#include <hip/hip_fp16.h>
#include <cstddef>
#include <cstdint>

#define B_  256
#define T_  512
#define D_  128
#define H_  256
#define G3_ 768
#define C_  10

typedef _Float16 f16x8 __attribute__((ext_vector_type(8)));
typedef float    f32x4 __attribute__((ext_vector_type(4)));

__device__ __forceinline__ float sigmoid_f(float x) {
    return 1.0f / (1.0f + __expf(-x));
}
__device__ __forceinline__ float tanh_f(float x) {
    return 1.0f - 2.0f / (__expf(2.0f * x) + 1.0f);
}

__device__ __forceinline__ unsigned int packh2(float a, float b) {
    unsigned short lo = __half_as_ushort(__float2half(a));   // k even -> lo16
    unsigned short hi = __half_as_ushort(__float2half(b));   // k odd  -> hi16
    return (unsigned int)lo | ((unsigned int)hi << 16);
}

// ---------------------------------------------------------------------------
// Pack Whh[3H][H] fp32 -> f16 MFMA B-fragment stream for the scan.
// Fragment (w, nt, kt): wave w owns gate-cols c0 = g*256 + w*32 + (nt&1)*16
// (g = nt>>1), K-tile kt. Lane l: n = c0 + (l&15), k = kt*32 + (l>>4)*8 + i.
// (unchanged, harness-verified layout)
// ---------------------------------------------------------------------------
__global__ void k_pack_whh(const float* __restrict__ Whh, uint4* __restrict__ Wl) {
    const int wnt = blockIdx.x;          // w*6 + nt
    const int w  = wnt / 6;
    const int nt = wnt % 6;
    const int t  = threadIdx.x;
    const int kt = t >> 6;
    const int l  = t & 63;
    const int g  = nt >> 1;
    const int n  = g * 256 + w * 32 + (nt & 1) * 16 + (l & 15);
    const int k0 = kt * 32 + (l >> 4) * 8;
    const float* row = Whh + (size_t)n * H_ + k0;
    uint4 u;
    u.x = packh2(row[0], row[1]);
    u.y = packh2(row[2], row[3]);
    u.z = packh2(row[4], row[5]);
    u.w = packh2(row[6], row[7]);
    Wl[(size_t)wnt * 512 + t] = u;
}

// ---------------------------------------------------------------------------
// Pack Wih[768][K] fp32 -> f16 B-fragments for the gi GEMM. (unchanged)
// ---------------------------------------------------------------------------
__global__ void k_pack_wih(const float* __restrict__ W, uint4* __restrict__ Wp,
                           int K) {
    const int KT = K >> 5;
    const int f  = blockIdx.x * 4 + (threadIdx.x >> 6);
    const int l  = threadIdx.x & 63;
    const int ntile = f / KT;
    const int kt    = f - ntile * KT;
    const int n  = ntile * 16 + (l & 15);
    const int k0 = kt * 32 + (l >> 4) * 8;
    const float* row = W + (size_t)n * K + k0;
    uint4 u;
    u.x = packh2(row[0], row[1]);
    u.y = packh2(row[2], row[3]);
    u.z = packh2(row[4], row[5]);
    u.w = packh2(row[6], row[7]);
    Wp[(size_t)f * 64 + l] = u;
}

// ---------------------------------------------------------------------------
// gi GEMM on the matrix pipe. C is written in SCAN-NATIVE order: for gate
// column n (g = n>>8, j = n&255, w = j>>5, cc = j&15, half = (j>>4)&1) the
// float goes to row-offset ((w*16+cc)*3 + g)*2 + half. The scan lane (w,c)
// then reads its 6 pre-activations as 3 contiguous float2 (zero addr VALU).
// ---------------------------------------------------------------------------
__global__ __launch_bounds__(256) void k_gemm_f16(
    const float* __restrict__ A, long Abstride, int tcShift,
    const uint4* __restrict__ Wp,
    const float* __restrict__ bias, float* __restrict__ C,
    int K)
{
    const int tid = threadIdx.x;
    const int w  = tid >> 6;
    const int l  = tid & 63;
    const int c  = l & 15;
    const int g4 = l >> 4;
    const int m0 = blockIdx.y * 128;
    const int n0 = blockIdx.x * 64;
    const int KT = K >> 5;
    const int mask = (1 << tcShift) - 1;

    const float* Arow0;
    const float* Arow1;
    {
        int mg0 = m0 + w * 32 + c;
        int mg1 = mg0 + 16;
        Arow0 = A + (size_t)(mg0 >> tcShift) * Abstride + (size_t)(mg0 & mask) * K + g4 * 8;
        Arow1 = A + (size_t)(mg1 >> tcShift) * Abstride + (size_t)(mg1 & mask) * K + g4 * 8;
    }
    const uint4* Wb = Wp + (size_t)((n0 >> 4) * KT) * 64 + l;

    f32x4 acc[2][4] = {};

    for (int kt = 0; kt < KT; kt++) {
        f16x8 a0, a1;
        {
            float4 lo = *(const float4*)(Arow0 + kt * 32);
            float4 hi = *(const float4*)(Arow0 + kt * 32 + 4);
            a0[0] = (_Float16)lo.x; a0[1] = (_Float16)lo.y;
            a0[2] = (_Float16)lo.z; a0[3] = (_Float16)lo.w;
            a0[4] = (_Float16)hi.x; a0[5] = (_Float16)hi.y;
            a0[6] = (_Float16)hi.z; a0[7] = (_Float16)hi.w;
        }
        {
            float4 lo = *(const float4*)(Arow1 + kt * 32);
            float4 hi = *(const float4*)(Arow1 + kt * 32 + 4);
            a1[0] = (_Float16)lo.x; a1[1] = (_Float16)lo.y;
            a1[2] = (_Float16)lo.z; a1[3] = (_Float16)lo.w;
            a1[4] = (_Float16)hi.x; a1[5] = (_Float16)hi.y;
            a1[6] = (_Float16)hi.z; a1[7] = (_Float16)hi.w;
        }
#pragma unroll
        for (int ct = 0; ct < 4; ct++) {
            uint4 wf = Wb[(size_t)(ct * KT + kt) * 64];
            acc[0][ct] = __builtin_amdgcn_mfma_f32_16x16x32_f16(
                a0, __builtin_bit_cast(f16x8, wf), acc[0][ct], 0, 0, 0);
            acc[1][ct] = __builtin_amdgcn_mfma_f32_16x16x32_f16(
                a1, __builtin_bit_cast(f16x8, wf), acc[1][ct], 0, 0, 0);
        }
    }

    // scan-native scatter (stride-24B across lanes; L2 absorbs)
#pragma unroll
    for (int ct = 0; ct < 4; ct++) {
        const int n = n0 + ct * 16 + c;
        const float bv = bias[n];
        const int g = n >> 8;
        const int j = n & 255;
        const int sidx = (((j >> 5) * 16 + (j & 15)) * 3 + g) * 2 + ((j >> 4) & 1);
#pragma unroll
        for (int rt = 0; rt < 2; rt++) {
#pragma unroll
            for (int rg = 0; rg < 4; rg++) {
                const int m = m0 + w * 32 + rt * 16 + g4 * 4 + rg;
                C[(size_t)m * G3_ + sidx] = acc[rt][ct][rg] + bv;
            }
        }
    }
}

// ---------------------------------------------------------------------------
// MFMA scan. R4 structure (32 blocks x 512 thr, 148 KB LDS, 1 blk/CU) with
// two targeted changes:
//  (1) BATCHED per-step weight loads: pointer laundered per step (no hoist/
//      CSE), all 32 f16x8 frags loaded at step top, then VALUE-laundered
//      (no sink into the k-loop). R1's remat placed each load at its MFMA
//      use -> exposed L2 latency per load with only 2 waves/SIMD; batching
//      issues 32 loads back-to-back and waits once, overlapped with gi
//      issue. Live ranges are intra-step -> no R2 AGPR shuttle, no R3 pin.
//  (2) gi reads are 3x float2 from the scan-native layout via uniform step
//      base (+tt*G3) + loop-invariant lane voffset + imm -- 12 loads, zero
//      per-step address VALU (was 24 scalar loads + 64-bit math).
// R6's cross-CU partner split measured 8.4 us/step (fence+flag ~5.5 us) --
// cross-block per-step sync is not viable; do not revisit.
// ---------------------------------------------------------------------------
__device__ __forceinline__ void gru_scan_core(
    const float* __restrict__ gi,      // + b0*Tc*G3   [16 rows][Tc][3H native]
    const uint4* __restrict__ Wpk,     // [48*8][64] packed B-fragments
    const float* __restrict__ bhh,
    float* __restrict__ h_state,       // + b0*H
    float* __restrict__ out_seq,       // + b0*Tc*H or nullptr
    int Tc, int initZero,
    uint4 (&lds_w)[8192], _Float16 (&lds_h)[2][16][264])
{
    const int tid = threadIdx.x;
    const int w  = tid >> 6;       // wave 0..7
    const int l  = tid & 63;
    const int c  = l & 15;
    const int g4 = l >> 4;         // 0..3

    // ---- stage LDS-resident weight frags (nt 4,5 of every wave) -----------
#pragma unroll
    for (int i = 0; i < 16; i++) {
        int idx = i * 512 + tid;                       // (wv*16 + fl)*64 + ln
        lds_w[idx] = Wpk[(size_t)(idx >> 10) * 3072 + 2048 + (idx & 1023)];
    }

    const int jA = w * 32 + c;
    const float br0 = bhh[jA],       br1 = bhh[jA + 16];
    const float bz0 = bhh[256 + jA], bz1 = bhh[256 + jA + 16];
    const float bn0 = bhh[512 + jA], bn1 = bhh[512 + jA + 16];

    // loop-invariant lane offsets (elements)
    int voff_gi[4], voff_os[4];
#pragma unroll
    for (int r = 0; r < 4; r++) {
        const int m = g4 * 4 + r;
        voff_gi[r] = m * Tc * G3_ + (w * 16 + c) * 6;
        voff_os[r] = m * Tc * H_ + jA;
    }
    const uint4* wptr = Wpk + (size_t)(w * 6 * 8) * 64 + l;  // nt0..3 base

    float hreg[4][2];
#pragma unroll
    for (int r = 0; r < 4; r++) {
        const int m = g4 * 4 + r;
        if (initZero) {
            hreg[r][0] = 0.0f;
            hreg[r][1] = 0.0f;
        } else {
            hreg[r][0] = h_state[(size_t)m * H_ + jA];
            hreg[r][1] = h_state[(size_t)m * H_ + jA + 16];
        }
        lds_h[0][m][jA]      = (_Float16)hreg[r][0];
        lds_h[0][m][jA + 16] = (_Float16)hreg[r][1];
    }
    __syncthreads();

    int cur = 0;
    for (int tt = 0; tt < Tc; ++tt) {
        // ---- batched weight loads: opaque pointer -> must issue here ------
        const uint4* wp = wptr;
        asm volatile("" : "+v"(wp));
        f16x8 wreg[32];
#pragma unroll
        for (int i = 0; i < 32; i++)
            wreg[i] = *reinterpret_cast<const f16x8*>(wp + (size_t)i * 64);

        // gi loads (overlap with weight-load latency)
        const float* gstep = gi + (size_t)tt * G3_;
        float2 vg[4][3];
#pragma unroll
        for (int r = 0; r < 4; r++) {
            const float* gp = gstep + voff_gi[r];
            vg[r][0] = *(const float2*)gp;
            vg[r][1] = *(const float2*)(gp + 2);
            vg[r][2] = *(const float2*)(gp + 4);
        }

        // value launder: weight frags complete HERE (one batched wait),
        // cannot be sunk into the k-loop.
#pragma unroll
        for (int i = 0; i < 32; i++)
            asm volatile("" : "+v"(wreg[i]));

        // LDS frag offset launder (keeps nt4,5 reads un-hoisted, as R1)
        unsigned wb = (unsigned)(w * 1024 + l);
        asm volatile("" : "+v"(wb));

        f32x4 acc[6] = {};
#pragma unroll
        for (int kt = 0; kt < 8; kt++) {
            f16x8 a = *(const f16x8*)&lds_h[cur][c][kt * 32 + g4 * 8];
#pragma unroll
            for (int nt = 0; nt < 4; nt++)
                acc[nt] = __builtin_amdgcn_mfma_f32_16x16x32_f16(
                    a, wreg[nt * 8 + kt], acc[nt], 0, 0, 0);
            uint4 u4 = lds_w[wb + kt * 64];            // nt=4 frag
            acc[4] = __builtin_amdgcn_mfma_f32_16x16x32_f16(
                a, __builtin_bit_cast(f16x8, u4), acc[4], 0, 0, 0);
            uint4 u5 = lds_w[wb + (8 + kt) * 64];      // nt=5 frag
            acc[5] = __builtin_amdgcn_mfma_f32_16x16x32_f16(
                a, __builtin_bit_cast(f16x8, u5), acc[5], 0, 0, 0);
        }

        // D layout: row m = g4*4 + reg, col = tile_c0 + c.
        // nt 0/1 = r-gate (jj=0/1), nt 2/3 = z, nt 4/5 = n.
        float* osb = out_seq ? out_seq + (size_t)tt * H_ : nullptr;
#pragma unroll
        for (int r = 0; r < 4; r++) {
            const int m = g4 * 4 + r;
#pragma unroll
            for (int jj = 0; jj < 2; jj++) {
                const float gr = jj ? vg[r][0].y : vg[r][0].x;
                const float gz = jj ? vg[r][1].y : vg[r][1].x;
                const float gn = jj ? vg[r][2].y : vg[r][2].x;
                float rg = sigmoid_f(gr + acc[jj][r]     + (jj ? br1 : br0));
                float zg = sigmoid_f(gz + acc[2 + jj][r] + (jj ? bz1 : bz0));
                float ng = tanh_f(gn + rg * (acc[4 + jj][r] + (jj ? bn1 : bn0)));
                float hn = (1.0f - zg) * ng + zg * hreg[r][jj];
                hreg[r][jj] = hn;
                lds_h[cur ^ 1][m][jA + jj * 16] = (_Float16)hn;
                if (osb)
                    osb[voff_os[r] + jj * 16] = hn;
            }
        }
        if (tt == Tc - 1) {
#pragma unroll
            for (int r = 0; r < 4; r++) {
                const int m = g4 * 4 + r;
                h_state[(size_t)m * H_ + jA]      = hreg[r][0];
                h_state[(size_t)m * H_ + jA + 16] = hreg[r][1];
            }
        }
        __syncthreads();
        cur ^= 1;
    }
}

// Fused layer-pipelined scan: blocks 0..15 -> layer0 chunk c (16 rows each),
// blocks 16..31 -> layer1 chunk c-1. 148 KB LDS -> 1 block/CU naturally.
__global__ __launch_bounds__(512, 2) void k_gru_scan_fused(
    const float* __restrict__ gi0, const uint4* __restrict__ wl0,
    const float* __restrict__ bhh0, float* __restrict__ hst0,
    float* __restrict__ h1c,
    const float* __restrict__ gi1, const uint4* __restrict__ wl1,
    const float* __restrict__ bhh1, float* __restrict__ hst1,
    int Tc, int do0, int do1, int init0, int init1)
{
    __shared__ __align__(16) uint4    lds_w[8192];        // 128 KB
    __shared__ __align__(16) _Float16 lds_h[2][16][264];  // 16.5 KB

    const int blk = blockIdx.x;
    if (blk < 16) {
        if (!do0) return;
        const int b0 = blk * 16;
        gru_scan_core(gi0 + (size_t)b0 * Tc * G3_, wl0, bhh0,
                      hst0 + (size_t)b0 * H_, h1c + (size_t)b0 * Tc * H_,
                      Tc, init0, lds_w, lds_h);
    } else {
        if (!do1) return;
        const int b0 = (blk - 16) * 16;
        gru_scan_core(gi1 + (size_t)b0 * Tc * G3_, wl1, bhh1,
                      hst1 + (size_t)b0 * H_, nullptr,
                      Tc, init1, lds_w, lds_h);
    }
}

// ---------------------------------------------------------------------------
__global__ void k_fc(const float* __restrict__ h, const float* __restrict__ Wfc,
                     const float* __restrict__ bfc, float* __restrict__ out)
{
    int idx = blockIdx.x * blockDim.x + threadIdx.x;
    if (idx >= B_ * C_) return;
    int b = idx / C_, c = idx % C_;
    const float* hp = h + (size_t)b * H_;
    const float* wp = Wfc + (size_t)c * H_;
    float s = bfc[c];
#pragma unroll 4
    for (int k = 0; k < H_; k++) s = fmaf(hp[k], wp[k], s);
    out[idx] = s;
}

// ---------------------------------------------------------------------------
extern "C" void kernel_launch(void* const* d_in, const int* in_sizes, int n_in,
                              void* d_out, int out_size, void* d_ws, size_t ws_size,
                              hipStream_t stream)
{
    const float* x    = (const float*)d_in[0];
    const float* Wih0 = (const float*)d_in[1];
    const float* Whh0 = (const float*)d_in[2];
    const float* bih0 = (const float*)d_in[3];
    const float* bhh0 = (const float*)d_in[4];
    const float* Wih1 = (const float*)d_in[5];
    const float* Whh1 = (const float*)d_in[6];
    const float* bih1 = (const float*)d_in[7];
    const float* bhh1 = (const float*)d_in[8];
    const float* Wfc  = (const float*)d_in[9];
    const float* bfc  = (const float*)d_in[10];
    float* out = (float*)d_out;

    const size_t wlBytes  = (size_t)48 * 512 * sizeof(uint4);    // 393,216 B
    const size_t wp0Bytes = (size_t)48 * 4 * 64 * sizeof(uint4); // 196,608 B
    const size_t wp1Bytes = (size_t)48 * 8 * 64 * sizeof(uint4); // 393,216 B

    // ---- largest power-of-two T-chunk that fits ws_size -------------------
    const size_t fixedB = 2 * wlBytes + wp0Bytes + wp1Bytes
                        + 2 * (size_t)B_ * H_ * 4 + 16384;
    int Tc = 128, tcShift = 7;
    while (Tc > 1) {
        size_t need = fixedB
                    + 2 * (size_t)B_ * Tc * G3_ * 4    // gi0, gi1 chunks
                    + (size_t)B_ * Tc * H_ * 4;        // h1 chunk
        if (need <= ws_size) break;
        Tc >>= 1; tcShift--;
    }
    const int nChunks = T_ / Tc;

    char* ws = (char*)d_ws;
    size_t off = 0;
    auto alloc = [&](size_t bytes) { char* p = ws + off; off += (bytes + 255) & ~(size_t)255; return p; };
    float* gi0  = (float*)alloc((size_t)B_ * Tc * G3_ * 4);
    float* gi1  = (float*)alloc((size_t)B_ * Tc * G3_ * 4);
    float* h1c  = (float*)alloc((size_t)B_ * Tc * H_ * 4);
    uint4* wl0  = (uint4*)alloc(wlBytes);
    uint4* wl1  = (uint4*)alloc(wlBytes);
    uint4* wp0  = (uint4*)alloc(wp0Bytes);
    uint4* wp1  = (uint4*)alloc(wp1Bytes);
    float* hst0 = (float*)alloc((size_t)B_ * H_ * 4);
    float* hst1 = (float*)alloc((size_t)B_ * H_ * 4);

    k_pack_whh<<<48, 512, 0, stream>>>(Whh0, wl0);
    k_pack_whh<<<48, 512, 0, stream>>>(Whh1, wl1);
    k_pack_wih<<<48, 256, 0, stream>>>(Wih0, wp0, D_);   // KT=4 -> 192 frags
    k_pack_wih<<<96, 256, 0, stream>>>(Wih1, wp1, H_);   // KT=8 -> 384 frags

    const dim3 ggrid(G3_ / 64, (B_ * Tc) / 128);

    // software pipeline: fused launch c runs scan0(c) and scan1(c-1)
    k_gemm_f16<<<ggrid, 256, 0, stream>>>(
        x, (long)T_ * D_, tcShift, wp0, bih0, gi0, D_);
    k_gru_scan_fused<<<32, 512, 0, stream>>>(
        gi0, wl0, bhh0, hst0, h1c, gi1, wl1, bhh1, hst1,
        Tc, 1, 0, 1, 0);

    for (int c = 1; c < nChunks; ++c) {
        k_gemm_f16<<<ggrid, 256, 0, stream>>>(
            h1c, (long)Tc * H_, tcShift, wp1, bih1, gi1, H_);        // chunk c-1
        k_gemm_f16<<<ggrid, 256, 0, stream>>>(
            x + (size_t)c * Tc * D_, (long)T_ * D_, tcShift, wp0, bih0, gi0, D_);
        k_gru_scan_fused<<<32, 512, 0, stream>>>(
            gi0, wl0, bhh0, hst0, h1c, gi1, wl1, bhh1, hst1,
            Tc, 1, 1, 0, c == 1);
    }

    k_gemm_f16<<<ggrid, 256, 0, stream>>>(
        h1c, (long)Tc * H_, tcShift, wp1, bih1, gi1, H_);            // last chunk
    k_gru_scan_fused<<<32, 512, 0, stream>>>(
        gi0, wl0, bhh0, hst0, h1c, gi1, wl1, bhh1, hst1,
        Tc, 0, 1, 0, nChunks == 1);

    k_fc<<<10, 256, 0, stream>>>(hst1, Wfc, bfc, out);
}